// Round 4
// baseline (1154.445 us; speedup 1.0000x reference)
//
#include <hip/hip_runtime.h>

#define NN 384
#define MM 128
#define TT 768
#define NITERS 100
#define KBUD 40.0f
#define LR_C 0.1f
#define MOM_C 0.9f

__device__ __forceinline__ unsigned sortable_bits(float f) {
    unsigned u = __float_as_uint(f);
    return (u & 0x80000000u) ? ~u : (u | 0x80000000u);
}

__device__ __forceinline__ float med01(float x) {
    return __builtin_amdgcn_fmed3f(x, 0.0f, 1.0f);
}

// quad (4-lane) sum via DPP quad_perm: lanes 4b..4b+3 all get the 4-lane sum
__device__ __forceinline__ float qsum(float x) {
    int a = __builtin_amdgcn_update_dpp(0, __float_as_int(x), 0xB1, 0xF, 0xF, true); // [1,0,3,2]
    float s1 = x + __int_as_float(a);
    int b = __builtin_amdgcn_update_dpp(0, __float_as_int(s1), 0x4E, 0xF, 0xF, true); // [2,3,0,1]
    return s1 + __int_as_float(b);
}

__global__ __launch_bounds__(TT, 3) void submod_kernel(
    const float* __restrict__ Y,    // [NN][MM] row-major
    const float* __restrict__ Z0,   // [NN]
    float* __restrict__ out)        // [NN]
{
    __shared__ __align__(16) float Wv[NN];        // Znew, then W
    __shared__ __align__(16) float Zb[NN];        // current Z
    __shared__ __align__(16) float Pcol[MM];
    __shared__ __align__(16) float partP[24][132];  // [rchunk][col(+pad)]
    __shared__ __align__(16) float partG[NN][33];   // [row][cgroup(+pad)]
    __shared__ __align__(16) float Hbp[2*NN];
    __shared__ float sAlpha;

    const int tid = threadIdx.x;
    const int cg = tid & 31;            // col-group: cols cg*4..+3
    const int rc = tid >> 5;            // row-chunk: rows rc*16..+15
    const int c0 = cg * 4;
    const int r0v = rc * 16;

    // ---- permanent Y block in registers: 16 rows x 4 cols = 16 float4 ----
    const float* Yp = Y + r0v * MM + c0;
    float4 y0  = *(const float4*)(Yp +  0*MM), y1  = *(const float4*)(Yp +  1*MM);
    float4 y2  = *(const float4*)(Yp +  2*MM), y3  = *(const float4*)(Yp +  3*MM);
    float4 y4  = *(const float4*)(Yp +  4*MM), y5  = *(const float4*)(Yp +  5*MM);
    float4 y6  = *(const float4*)(Yp +  6*MM), y7  = *(const float4*)(Yp +  7*MM);
    float4 y8  = *(const float4*)(Yp +  8*MM), y9  = *(const float4*)(Yp +  9*MM);
    float4 y10 = *(const float4*)(Yp + 10*MM), y11 = *(const float4*)(Yp + 11*MM);
    float4 y12 = *(const float4*)(Yp + 12*MM), y13 = *(const float4*)(Yp + 13*MM);
    float4 y14 = *(const float4*)(Yp + 14*MM), y15 = *(const float4*)(Yp + 15*MM);

    if (tid < NN) { float z = Z0[tid]; Zb[tid] = z; Wv[tid] = z; }
    __syncthreads();

    const int bpg = tid >> 2, qh = tid & 3;
    const int pb  = bpg * 4;
    const int wb  = (pb < NN) ? pb : pb - NN;
    const float subv = (pb < NN) ? 1.0f : 0.0f;

    for (int it = 0; it < NITERS; ++it) {
        // ---- read this thread's 16 Znew values (rows r0v..+15) ----
        const float4* Wv4 = (const float4*)Wv;
        float4 za = Wv4[rc*4+0], zb4 = Wv4[rc*4+1];
        float4 zc = Wv4[rc*4+2], zd = Wv4[rc*4+3];

        // ---- phase P: 4 column-partials over 16 rows (pure registers) ----
        {
            float p0 = 1.f, p1 = 1.f, p2 = 1.f, p3 = 1.f;
#define PSTEP(yv, zf) { p0 *= fmaf(-(yv).x,(zf),1.f); p1 *= fmaf(-(yv).y,(zf),1.f); \
                        p2 *= fmaf(-(yv).z,(zf),1.f); p3 *= fmaf(-(yv).w,(zf),1.f); }
            PSTEP(y0, za.x)  PSTEP(y1, za.y)  PSTEP(y2, za.z)  PSTEP(y3, za.w)
            PSTEP(y4, zb4.x) PSTEP(y5, zb4.y) PSTEP(y6, zb4.z) PSTEP(y7, zb4.w)
            PSTEP(y8, zc.x)  PSTEP(y9, zc.y)  PSTEP(y10, zc.z) PSTEP(y11, zc.w)
            PSTEP(y12, zd.x) PSTEP(y13, zd.y) PSTEP(y14, zd.z) PSTEP(y15, zd.w)
#undef PSTEP
            float4 p4; p4.x = p0; p4.y = p1; p4.z = p2; p4.w = p3;
            *(float4*)&partP[rc][c0] = p4;
        }
        __syncthreads();                                   // B1

        if (tid < MM) {     // Pcol[c] = product of 24 chunk-partials
            float a = 1.f, b = 1.f, c = 1.f;
            #pragma unroll
            for (int m = 0; m < 24; m += 3) {
                a *= partP[m][tid]; b *= partP[m+1][tid]; c *= partP[m+2][tid];
            }
            Pcol[tid] = (a * b) * c;
        }
        __syncthreads();                                   // B2

        // ---- phase G: 16 row-partials over this thread's 4 cols ----
        {
            float4 pq = ((const float4*)Pcol)[cg];
#define GTERM(yc, pc, zf, acc) { float t = fmaf(-(yc),(zf),1.f); \
            float rr = __builtin_amdgcn_rcpf(t); rr = rr * fmaf(-t, rr, 2.0f); \
            float cb = (yc)*(pc)*rr; acc += (t == 0.f) ? 0.f : cb; }
#define GSTEP(yv, zf, row) { float sa = 0.f, sb = 0.f; \
            GTERM((yv).x, pq.x, (zf), sa) GTERM((yv).y, pq.y, (zf), sb) \
            GTERM((yv).z, pq.z, (zf), sa) GTERM((yv).w, pq.w, (zf), sb) \
            partG[row][cg] = sa + sb; }
            GSTEP(y0, za.x, r0v+0)   GSTEP(y1, za.y, r0v+1)
            GSTEP(y2, za.z, r0v+2)   GSTEP(y3, za.w, r0v+3)
            GSTEP(y4, zb4.x, r0v+4)  GSTEP(y5, zb4.y, r0v+5)
            GSTEP(y6, zb4.z, r0v+6)  GSTEP(y7, zb4.w, r0v+7)
            GSTEP(y8, zc.x, r0v+8)   GSTEP(y9, zc.y, r0v+9)
            GSTEP(y10, zc.z, r0v+10) GSTEP(y11, zc.w, r0v+11)
            GSTEP(y12, zd.x, r0v+12) GSTEP(y13, zd.y, r0v+13)
            GSTEP(y14, zd.z, r0v+14) GSTEP(y15, zd.w, r0v+15)
#undef GSTEP
#undef GTERM
        }
        __syncthreads();                                   // B3

        if (tid < NN) {     // g_i = sum of 32 col-group partials; W = Znew + LR*g
            float ga = 0.f, gb = 0.f;
            #pragma unroll
            for (int q = 0; q < 32; q += 2) {
                ga += partG[tid][q]; gb += partG[tid][q+1];
            }
            Wv[tid] = fmaf(LR_C, ga + gb, Wv[tid]);
        }
        __syncthreads();                                   // B4

        // ---- phase H: h at 4 bps (pb..pb+3) over quarter qh, rotated reads ----
        {
            float4 av = *(const float4*)(Wv + wb);
            const float A0 = av.x - subv, A1 = av.y - subv;
            const float A2 = av.z - subv, A3 = av.w - subv;
            float h0 = 0.f, h1 = 0.f, h2 = 0.f, h3 = 0.f;
            const float4* W4q = (const float4*)(Wv + qh * 96);
            int m = qh * 6;
            #pragma unroll
            for (int s = 0; s < 24; ++s) {
                float4 w = W4q[m];
                ++m; if (m == 24) m = 0;
                h0 += med01(w.x-A0) + med01(w.y-A0) + med01(w.z-A0) + med01(w.w-A0);
                h1 += med01(w.x-A1) + med01(w.y-A1) + med01(w.z-A1) + med01(w.w-A1);
                h2 += med01(w.x-A2) + med01(w.y-A2) + med01(w.z-A2) + med01(w.w-A2);
                h3 += med01(w.x-A3) + med01(w.y-A3) + med01(w.z-A3) + med01(w.w-A3);
            }
            // cross-quarter sum via DPP (qh lanes are adjacent); lane qh keeps bp pb+qh
            float s0 = qsum(h0), s1 = qsum(h1), s2 = qsum(h2), s3 = qsum(h3);
            float hsel = (qh == 0) ? s0 : (qh == 1) ? s1 : (qh == 2) ? s2 : s3;
            Hbp[tid] = hsel;   // tid == pb + qh
        }
        __syncthreads();                                   // B5

        // ---- wave-0 reduce: a_hi = min bp with h<k; a_lo = max bp < a_hi ----
        if (tid < 64) {
            unsigned long long mCond = ~0ull;
            #pragma unroll
            for (int c2 = 0; c2 < 12; ++c2) {
                int p = c2 * 64 + tid;
                float a = (p < NN) ? (Wv[p] - 1.0f) : Wv[p - NN];
                float h = Hbp[p];
                unsigned long long pk =
                    ((unsigned long long)sortable_bits(a) << 32) | (unsigned)p;
                if (h < KBUD && pk < mCond) mCond = pk;
            }
            #pragma unroll
            for (int d = 1; d < 64; d <<= 1) {
                unsigned long long o = __shfl_xor(mCond, d);
                if (o < mCond) mCond = o;
            }
            int pHi = (int)(mCond & 0xffffffffu);
            float aHi = (pHi < NN) ? (Wv[pHi] - 1.0f) : Wv[pHi - NN];
            float hHi = Hbp[pHi];

            unsigned long long mLo = 0ull;
            #pragma unroll
            for (int c2 = 0; c2 < 12; ++c2) {
                int p = c2 * 64 + tid;
                float a = (p < NN) ? (Wv[p] - 1.0f) : Wv[p - NN];
                unsigned long long pk =
                    ((unsigned long long)sortable_bits(a) << 32) | (unsigned)p;
                if (a < aHi && pk > mLo) mLo = pk;
            }
            #pragma unroll
            for (int d = 1; d < 64; d <<= 1) {
                unsigned long long o = __shfl_xor(mLo, d);
                if (o > mLo) mLo = o;
            }
            if (tid == 0) {
                int pLo = (int)(mLo & 0xffffffffu);
                float aLo = (pLo < NN) ? (Wv[pLo] - 1.0f) : Wv[pLo - NN];
                float hLo = Hbp[pLo];
                sAlpha = aLo + (aHi - aLo) * (hLo - KBUD) / (hLo - hHi);
            }
        }
        __syncthreads();                                   // B6

        // ---- fused: Z = clip(W-a); Wv = Znew_next = Z + MOM*(Z - Zold) ----
        if (tid < NN) {
            float w  = Wv[tid];
            float zn = med01(w - sAlpha);
            float zcur = Zb[tid];
            Zb[tid] = zn;
            Wv[tid] = fmaf(MOM_C, zn - zcur, zn);
        }
        __syncthreads();                                   // B7
    }

    if (tid < NN) out[tid] = Zb[tid];
}

extern "C" void kernel_launch(void* const* d_in, const int* in_sizes, int n_in,
                              void* d_out, int out_size, void* d_ws, size_t ws_size,
                              hipStream_t stream) {
    const float* Y  = (const float*)d_in[0];   // Yhat [384*128]
    const float* Z0 = (const float*)d_in[1];   // Z_init [384]
    float* out = (float*)d_out;
    (void)d_ws; (void)ws_size;
    submod_kernel<<<1, TT, 0, stream>>>(Y, Z0, out);
}

// Round 5
// 923.821 us; speedup vs baseline: 1.2496x; 1.2496x over previous
//
#include <hip/hip_runtime.h>

#define NN 384
#define MM 128
#define TT 768
#define NITERS 100
#define KBUD 40.0f
#define LR_C 0.1f
#define MOM_C 0.9f

__device__ __forceinline__ float med01(float x) {
    return __builtin_amdgcn_fmed3f(x, 0.0f, 1.0f);
}

__global__ __launch_bounds__(TT, 1) void submod_kernel(
    const float* __restrict__ Y,    // [NN][MM] row-major
    const float* __restrict__ Z0,   // [NN]
    float* __restrict__ out)        // [NN]
{
    __shared__ __align__(16) float Wv[NN];        // Znew, then W
    __shared__ __align__(16) float Zb[NN];        // current Z
    __shared__ __align__(16) float Pcol[MM];
    __shared__ __align__(16) float partP[24][132];
    __shared__ float sAlpha;

    const int tid = threadIdx.x;
    const int cg  = tid & 31;           // col-group: cols cg*4..+3
    const int rc  = tid >> 5;           // row-chunk: rows rc*16..+15
    const int c0  = cg * 4;
    const int r0v = rc * 16;

    // ---- permanent Y block in registers: 16 rows x 4 cols (64 VGPR) ----
    // launch_bounds(768,1): 1 block/CU -> 3 waves/SIMD -> ~170 VGPR budget.
    const float* Yp = Y + r0v * MM + c0;
    const float4 y0  = *(const float4*)(Yp +  0*MM), y1  = *(const float4*)(Yp +  1*MM);
    const float4 y2  = *(const float4*)(Yp +  2*MM), y3  = *(const float4*)(Yp +  3*MM);
    const float4 y4  = *(const float4*)(Yp +  4*MM), y5  = *(const float4*)(Yp +  5*MM);
    const float4 y6  = *(const float4*)(Yp +  6*MM), y7  = *(const float4*)(Yp +  7*MM);
    const float4 y8  = *(const float4*)(Yp +  8*MM), y9  = *(const float4*)(Yp +  9*MM);
    const float4 y10 = *(const float4*)(Yp + 10*MM), y11 = *(const float4*)(Yp + 11*MM);
    const float4 y12 = *(const float4*)(Yp + 12*MM), y13 = *(const float4*)(Yp + 13*MM);
    const float4 y14 = *(const float4*)(Yp + 14*MM), y15 = *(const float4*)(Yp + 15*MM);

    if (tid < NN) { float z = Z0[tid]; Zb[tid] = z; Wv[tid] = z; }
    if (tid == 0) sAlpha = 0.0f;
    __syncthreads();

    for (int it = 0; it < NITERS; ++it) {
        // ---- this thread's 16 Znew values (rows r0v..r0v+15) ----
        const float4* Wv4 = (const float4*)Wv;
        const float4 za  = Wv4[rc*4+0], zbv = Wv4[rc*4+1];
        const float4 zcv = Wv4[rc*4+2], zdv = Wv4[rc*4+3];

        // ---- phase P: 4 column-partials over 16 rows (pure registers) ----
        {
            float pp0 = 1.f, pp1 = 1.f, pp2 = 1.f, pp3 = 1.f;
#define PSTEP(yv, zf) { pp0 *= fmaf(-(yv).x,(zf),1.f); pp1 *= fmaf(-(yv).y,(zf),1.f); \
                        pp2 *= fmaf(-(yv).z,(zf),1.f); pp3 *= fmaf(-(yv).w,(zf),1.f); }
            PSTEP(y0,  za.x)  PSTEP(y1,  za.y)  PSTEP(y2,  za.z)  PSTEP(y3,  za.w)
            PSTEP(y4,  zbv.x) PSTEP(y5,  zbv.y) PSTEP(y6,  zbv.z) PSTEP(y7,  zbv.w)
            PSTEP(y8,  zcv.x) PSTEP(y9,  zcv.y) PSTEP(y10, zcv.z) PSTEP(y11, zcv.w)
            PSTEP(y12, zdv.x) PSTEP(y13, zdv.y) PSTEP(y14, zdv.z) PSTEP(y15, zdv.w)
#undef PSTEP
            float4 p4; p4.x = pp0; p4.y = pp1; p4.z = pp2; p4.w = pp3;
            *(float4*)&partP[rc][c0] = p4;
        }
        __syncthreads();                                   // B1

        if (tid < MM) {     // Pcol[c] = product of 24 chunk-partials
            float a = 1.f, b = 1.f, c = 1.f;
            #pragma unroll
            for (int m = 0; m < 24; m += 3) {
                a *= partP[m][tid]; b *= partP[m+1][tid]; c *= partP[m+2][tid];
            }
            Pcol[tid] = (a * b) * c;
        }
        __syncthreads();                                   // B2

        // ---- phase G: row-partials over 4 cols, butterfly-reduced in-wave,
        //      W[row] = Znew + LR*g written directly (rows owned per 32-lane grp)
        {
            const float4 pq = ((const float4*)Pcol)[cg];
            float p0,p1,p2,p3,p4,p5,p6,p7,p8,p9,p10,p11,p12,p13,p14,p15;
#define GROW(yv, zf, pr) { float sa, sb; \
    { float t = fmaf(-(yv).x,(zf),1.f); float cb = (yv).x*pq.x*__builtin_amdgcn_rcpf(t); sa = (t==0.f)?0.f:cb; } \
    { float t = fmaf(-(yv).y,(zf),1.f); float cb = (yv).y*pq.y*__builtin_amdgcn_rcpf(t); sb = (t==0.f)?0.f:cb; } \
    { float t = fmaf(-(yv).z,(zf),1.f); float cb = (yv).z*pq.z*__builtin_amdgcn_rcpf(t); sa += (t==0.f)?0.f:cb; } \
    { float t = fmaf(-(yv).w,(zf),1.f); float cb = (yv).w*pq.w*__builtin_amdgcn_rcpf(t); sb += (t==0.f)?0.f:cb; } \
    pr = sa + sb; }
            GROW(y0,  za.x,  p0)  GROW(y1,  za.y,  p1)
            GROW(y2,  za.z,  p2)  GROW(y3,  za.w,  p3)
            GROW(y4,  zbv.x, p4)  GROW(y5,  zbv.y, p5)
            GROW(y6,  zbv.z, p6)  GROW(y7,  zbv.w, p7)
            GROW(y8,  zcv.x, p8)  GROW(y9,  zcv.y, p9)
            GROW(y10, zcv.z, p10) GROW(y11, zcv.w, p11)
            GROW(y12, zdv.x, p12) GROW(y13, zdv.y, p13)
            GROW(y14, zdv.z, p14) GROW(y15, zdv.w, p15)
#undef GROW
            // butterfly over the 32 lanes sharing rc (masks <32 stay in-group)
#define BFLY(mk) { p0 += __shfl_xor(p0, mk);  p1 += __shfl_xor(p1, mk); \
                   p2 += __shfl_xor(p2, mk);  p3 += __shfl_xor(p3, mk); \
                   p4 += __shfl_xor(p4, mk);  p5 += __shfl_xor(p5, mk); \
                   p6 += __shfl_xor(p6, mk);  p7 += __shfl_xor(p7, mk); \
                   p8 += __shfl_xor(p8, mk);  p9 += __shfl_xor(p9, mk); \
                   p10 += __shfl_xor(p10, mk); p11 += __shfl_xor(p11, mk); \
                   p12 += __shfl_xor(p12, mk); p13 += __shfl_xor(p13, mk); \
                   p14 += __shfl_xor(p14, mk); p15 += __shfl_xor(p15, mk); }
            BFLY(1) BFLY(2) BFLY(4) BFLY(8) BFLY(16)
#undef BFLY
            // static select-tree: lane cg<16 picks p[cg], writes row r0v+cg
            const int b0 = cg & 1, b1 = cg & 2, b2 = cg & 4, b3 = cg & 8;
            float q0 = b0 ? p1  : p0,  q1 = b0 ? p3  : p2;
            float q2 = b0 ? p5  : p4,  q3 = b0 ? p7  : p6;
            float q4 = b0 ? p9  : p8,  q5 = b0 ? p11 : p10;
            float q6 = b0 ? p13 : p12, q7 = b0 ? p15 : p14;
            float r0 = b1 ? q1 : q0, r1 = b1 ? q3 : q2;
            float r2 = b1 ? q5 : q4, r3 = b1 ? q7 : q6;
            float s0 = b2 ? r1 : r0, s1 = b2 ? r3 : r2;
            float gsum = b3 ? s1 : s0;
            if (cg < 16) {
                int row = r0v + cg;
                Wv[row] = fmaf(LR_C, gsum, Wv[row]);
            }
        }
        __syncthreads();                                   // B3

        // ---- solver: alpha* = root of h(a) = sum med01(W-a) = k (wave 0) ----
        if (tid < 64) {
            float w0 = Wv[tid      ], w1 = Wv[tid +  64], w2 = Wv[tid + 128];
            float w3 = Wv[tid + 192], w4 = Wv[tid + 256], w5 = Wv[tid + 320];
            float mn = fminf(fminf(fminf(w0,w1),fminf(w2,w3)),fminf(w4,w5));
            float mx = fmaxf(fmaxf(fmaxf(w0,w1),fmaxf(w2,w3)),fmaxf(w4,w5));
            #pragma unroll
            for (int d = 1; d < 64; d <<= 1) {
                mn = fminf(mn, __shfl_xor(mn, d));
                mx = fmaxf(mx, __shfl_xor(mx, d));
            }
            float lo = mn - 1.0f;           // h(lo) = 384 > k
            float hi = mx;                  // h(hi) = 0   < k
            float alpha = __builtin_amdgcn_fmed3f(sAlpha, lo, hi);  // warm start
            #pragma unroll
            for (int itr = 0; itr < 12; ++itr) {
                float h = 0.f, nA = 0.f;
#define HTERM(w) { float d = (w) - alpha; \
                   h  += med01(d); \
                   nA += (d > 0.f && d < 1.f) ? 1.f : 0.f; }
                HTERM(w0) HTERM(w1) HTERM(w2) HTERM(w3) HTERM(w4) HTERM(w5)
#undef HTERM
                #pragma unroll
                for (int d = 1; d < 64; d <<= 1) {
                    h  += __shfl_xor(h, d);
                    nA += __shfl_xor(nA, d);
                }
                float dh = h - KBUD;        // >0: root is above alpha
                lo = (dh >= 0.f) ? alpha : lo;
                hi = (dh <= 0.f) ? alpha : hi;   // dh==0 collapses bracket
                float r  = __builtin_amdgcn_rcpf(nA);      // inf if nA==0
                float an = fmaf(dh, r, alpha);             // exact-piece solve
                alpha = (an > lo && an < hi) ? an : 0.5f * (lo + hi);
            }
            if (tid == 0) sAlpha = alpha;
        }
        __syncthreads();                                   // B4

        // ---- Z = clip(W - a); Wv = next Znew = Z + MOM*(Z - Zold) ----
        if (tid < NN) {
            float w    = Wv[tid];
            float zn   = med01(w - sAlpha);
            float zcur = Zb[tid];
            Zb[tid] = zn;
            Wv[tid] = fmaf(MOM_C, zn - zcur, zn);
        }
        __syncthreads();                                   // B5
    }

    if (tid < NN) out[tid] = Zb[tid];
}

extern "C" void kernel_launch(void* const* d_in, const int* in_sizes, int n_in,
                              void* d_out, int out_size, void* d_ws, size_t ws_size,
                              hipStream_t stream) {
    const float* Y  = (const float*)d_in[0];   // Yhat [384*128]
    const float* Z0 = (const float*)d_in[1];   // Z_init [384]
    float* out = (float*)d_out;
    (void)d_ws; (void)ws_size;
    submod_kernel<<<1, TT, 0, stream>>>(Y, Z0, out);
}